// Round 14
// baseline (74.277 us; speedup 1.0000x reference)
//
#include <hip/hip_runtime.h>
#include <hip/hip_bf16.h>

// CrossAttentionOutLayer: out[b,i,j] = (1/H) * sum_c Q'[b,i,c] * K[b,j,c]
//   Q' = SCALE*(rna@Wq.T + bq) + rel_bias   (c = h*DK+d == flat rel_bias idx)
//   K  = prot@Wk.T + bk
// B=8 N=1024 M=1024 DIM2=1280 KIN=1344 H=8 DK=64 HDK=512 SCALE=0.125
//
// R14: proj is LDS-BW-bound (R13 model closes: 208 KB/step -> 41 us floor,
// measured 59 with conflicts+drains). Minimize LDS bytes/FLOP:
// traffic = BM*64*4*(1+wn) + BN*64*2*(1+wm). New: BM=128 x BN=256, 4 waves
// (2x2), per-wave 64x128 (acc 4x8) -> 192 KB / 4.2 MFLOP = 46 B/KFLOP
// (R13: 100). 20 steps x 2260 cyc ~ 19 us LDS floor. Grid 256 (1/CU),
// LDS 64 KB. A-read conflict fix: 4-bit swizzle mask4(r)=((r&3)<<2)|((r>>2)&3)
// (bijective on 16 fr values -> 16 distinct chunks/instr = b128 floor);
// stage-side mask known per gload_lds instr. W: bf16 pre-swizzled HBM (R13).

typedef __bf16 bf16x8 __attribute__((ext_vector_type(8)));
typedef float f32x4 __attribute__((ext_vector_type(4)));

__device__ inline bf16x8 cvt2(const f32x4 a, const f32x4 b) {
    bf16x8 r;
    r[0] = (__bf16)a[0]; r[1] = (__bf16)a[1]; r[2] = (__bf16)a[2]; r[3] = (__bf16)a[3];
    r[4] = (__bf16)b[0]; r[5] = (__bf16)b[1]; r[6] = (__bf16)b[2]; r[7] = (__bf16)b[3];
    return r;
}

#define GLDS(src, dst) __builtin_amdgcn_global_load_lds( \
    (const __attribute__((address_space(1))) void*)(src), \
    (__attribute__((address_space(3))) void*)(dst), 16, 0, 0)

// ---------------------------------------------------------------------------
// Weight convert + swizzle (unchanged R13, refcheck-proven):
// wb[row][p] = orig[row][(p&~7) | ((p&7)^mask3(row&7))], mask3(r)=((r&3)<<1)|((r>>2)&1)
// ---------------------------------------------------------------------------
__global__ __launch_bounds__(256)
void wcvt(const float* __restrict__ Wq, const float* __restrict__ Wk,
          __bf16* __restrict__ wqb, __bf16* __restrict__ wkb)
{
    const int id = blockIdx.x * 256 + threadIdx.x;
    const int NQ = 512 * 160;
    const float* src; __bf16* dst; int row, p, K;
    if (id < NQ) { row = id / 160; p = id - row * 160; K = 1280; src = Wq; dst = wqb; }
    else { const int t = id - NQ; row = t / 168; p = t - row * 168; K = 1344; src = Wk; dst = wkb; }
    const int m3 = ((row & 3) << 1) | ((row >> 2) & 1);
    const int c  = (p & ~7) | ((p & 7) ^ m3);
    const f32x4 v0 = *(const f32x4*)(src + (size_t)row * K + c * 8);
    const f32x4 v1 = *(const f32x4*)(src + (size_t)row * K + c * 8 + 4);
    *(bf16x8*)(dst + (size_t)row * K + p * 8) = cvt2(v0, v1);
}

// ---------------------------------------------------------------------------
// Fused Q+K projection. BM=128 x BN=256 x BK=64; 4 waves (2x2), each 64x128.
// A: f32 in LDS (gload_lds, mask4 source swizzle); W: bf16 in LDS (gload_lds,
// HBM pre-swizzled). grid 256 (1/CU), bijective XCD swizzle.
// ---------------------------------------------------------------------------
__global__ __launch_bounds__(256, 1)
void proj_all(const float* __restrict__ rna,  const float* __restrict__ prot,
              const __bf16* __restrict__ wqb, const __bf16* __restrict__ wkb,
              const float* __restrict__ bq,   const float* __restrict__ bk,
              const float* __restrict__ rb,
              __bf16* __restrict__ qout, __bf16* __restrict__ kout)
{
    __shared__ float  As[128 * 64];   // 32 KB (f32, mask4-swizzled content)
    __shared__ __bf16 Ws[256 * 64];   // 32 KB (bf16, mask3-swizzled content)

    const int bid = blockIdx.x;
    const int wg  = (bid & 7) * 32 + (bid >> 3);   // bijective XCD swizzle (256%8==0)
    const bool isQ = wg < 128;
    const int lwg  = isQ ? wg : wg - 128;
    const int brow = (lwg >> 1) * 128;   // 64 row-tiles per matrix
    const int bcol = (lwg & 1) * 256;    // 2 col-tiles (N=512)

    const float*  A    = isQ ? rna : prot;
    const __bf16* Wb   = isQ ? wqb : wkb;
    const float*  bias = isQ ? bq  : bk;
    __bf16*       out  = isQ ? qout : kout;
    const int     K    = isQ ? 1280 : 1344;

    const int tid  = threadIdx.x;
    const int lane = tid & 63;
    const int wid  = tid >> 6;           // 0..3
    const int wr   = wid >> 1;           // 0..1 -> 64-row half
    const int wc   = wid & 1;            // 0..1 -> 128-col half
    const int fr   = lane & 15;
    const int q4   = lane >> 4;

    // ---- A staging: 8 instrs/wave; instr i: rows wid*32 + i*4 + lrow ----
    // mask4(row&15) = ((row&3)<<2)|((row>>2)&3); row&3=lrow, (row>>2)&3=i&3
    //   -> lane source chunk ci = (lane&15) ^ ((lrow<<2)|(i&3)).
    // 4 base pointers (j = i&3); i = j+4 adds 16 rows (+16*K floats).
    const int lrow = lane >> 4;
    const float* aB[4];
    #pragma unroll
    for (int j = 0; j < 4; ++j) {
        const int ci = (lane & 15) ^ ((lrow << 2) | j);
        aB[j] = A + (size_t)(brow + wid * 32 + j * 4 + lrow) * K + ci * 4;
    }

    // ---- W staging: 8 instrs/wave; instr j: rows wid*64 + j*8 + (l>>3),
    // chunk l&7 (source already bf16 + mask3-swizzled in HBM -> linear). ----
    const __bf16* wG = Wb + (size_t)(bcol + wid * 64 + (lane >> 3)) * K + (lane & 7) * 8;

    // fragment-read swizzles
    const int rmask4 = ((fr & 3) << 2) | (fr >> 2);        // A (16 chunks)
    const int rmask3 = ((fr & 3) << 1) | ((fr >> 2) & 1);  // W (8 chunks)

    f32x4 acc[4][8] = {};

    for (int k0 = 0; k0 < K; k0 += 64) {
        __syncthreads();                       // prev step's frag reads done
        #pragma unroll
        for (int i = 0; i < 8; ++i)
            GLDS(aB[i & 3] + (size_t)((i >> 2) * 16) * K + k0,
                 &As[(wid * 32 + i * 4) * 64]);
        #pragma unroll
        for (int j = 0; j < 8; ++j)
            GLDS(wG + (size_t)(j * 8) * K + k0,
                 &Ws[(wid * 64 + j * 8) * 64]);
        __syncthreads();                       // drains vmcnt -> tiles resident

        #pragma unroll
        for (int kk = 0; kk < 2; ++kk) {
            const int g0 = kk * 8 + 2 * q4;    // A global chunk pair g0, g0+1
            const int cw = kk * 4 + q4;        // W global chunk
            bf16x8 af[4], bw[8];
            #pragma unroll
            for (int m = 0; m < 4; ++m) {
                const float* rp = &As[(wr * 64 + m * 16 + fr) * 64];
                f32x4 u0 = *(const f32x4*)(rp + (((g0    ) ^ rmask4) << 2));
                f32x4 u1 = *(const f32x4*)(rp + (((g0 + 1) ^ rmask4) << 2));
                af[m] = cvt2(u0, u1);
            }
            #pragma unroll
            for (int n = 0; n < 8; ++n)
                bw[n] = *(const bf16x8*)(&Ws[(wc * 128 + n * 16 + fr) * 64
                                             + ((cw ^ rmask3) << 3)]);
            #pragma unroll
            for (int m = 0; m < 4; ++m)
                #pragma unroll
                for (int n = 0; n < 8; ++n)
                    acc[m][n] = __builtin_amdgcn_mfma_f32_16x16x32_bf16(af[m], bw[n], acc[m][n], 0, 0, 0);
        }
    }

    // C/D layout: col = lane&15, row = (lane>>4)*4 + j  [m89-verified]
    const int r0 = q4 * 4;
    #pragma unroll
    for (int n = 0; n < 8; ++n) {
        const int c = bcol + wc * 128 + n * 16 + fr;
        const float bv = bias[c];
        const float rv = isQ ? rb[c] : 0.0f;
        #pragma unroll
        for (int m = 0; m < 4; ++m) {
            const int row = brow + wr * 64 + m * 16 + r0;
            #pragma unroll
            for (int j = 0; j < 4; ++j) {
                float v = acc[m][n][j] + bv;
                if (isQ) v = 0.125f * v + rv;
                out[(size_t)(row + j) * 512 + c] = (__bf16)v;
            }
        }
    }
}

// ---------------------------------------------------------------------------
// Batched GEMM: out[b,i,j] = 0.125 * sum_c Q[b,i,c]*K[b,j,c]
// 128x128 tile, BK=64, gload_lds staging, swizzled bf16 LDS. (unchanged;
// ~9.6 us ~= its 96 KB/step LDS floor + HBM out-write)
// ---------------------------------------------------------------------------
__global__ __launch_bounds__(256, 2)
void attn_kernel(const __bf16* __restrict__ Q,
                 const __bf16* __restrict__ Kb,
                 float* __restrict__ out)
{
    __shared__ __bf16 As[128 * 64];   // 16 KB, linear dest (swizzled content)
    __shared__ __bf16 Bs[128 * 64];

    const int tid  = threadIdx.x;
    const int lane = tid & 63;
    const int wid  = tid >> 6;
    const int wr   = wid >> 1;
    const int wc   = wid & 1;
    const int b    = blockIdx.z;
    const int brow = blockIdx.y * 128;
    const int bcol = blockIdx.x * 128;

    const __bf16* Qb = Q  + (size_t)b * 1024 * 512;
    const __bf16* Kp = Kb + (size_t)b * 1024 * 512;

    const int fr = lane & 15;
    const int q4 = lane >> 4;

    f32x4 acc[4][4] = {};

    const int lr3 = lane >> 3;
    const int m3  = ((lr3 & 3) << 1) | ((lr3 >> 2) & 1);
    const int scol = ((lane & 7) ^ m3) * 8;            // swizzled global bf16 col
    const int rmask = ((fr & 3) << 1) | ((fr >> 2) & 1);

    for (int k0 = 0; k0 < 512; k0 += 64) {
        __syncthreads();
        #pragma unroll
        for (int i = 0; i < 4; ++i) {
            const int rbase = wid * 32 + i * 8;
            GLDS(Qb + (size_t)(brow + rbase + lr3) * 512 + k0 + scol, &As[rbase * 64]);
            GLDS(Kp + (size_t)(bcol + rbase + lr3) * 512 + k0 + scol, &Bs[rbase * 64]);
        }
        __syncthreads();

        #pragma unroll
        for (int kk = 0; kk < 2; ++kk) {
            const int ci = kk * 4 + q4;
            bf16x8 af[4], bf_[4];
            #pragma unroll
            for (int m = 0; m < 4; ++m)
                af[m] = *(const bf16x8*)(&As[(wr * 64 + m * 16 + fr) * 64 + ((ci ^ rmask) << 3)]);
            #pragma unroll
            for (int n = 0; n < 4; ++n)
                bf_[n] = *(const bf16x8*)(&Bs[(wc * 64 + n * 16 + fr) * 64 + ((ci ^ rmask) << 3)]);
            #pragma unroll
            for (int m = 0; m < 4; ++m)
                #pragma unroll
                for (int n = 0; n < 4; ++n)
                    acc[m][n] = __builtin_amdgcn_mfma_f32_16x16x32_bf16(af[m], bf_[n], acc[m][n], 0, 0, 0);
        }
    }

    float* op = out + (size_t)b * 1024 * 1024;
    const int r0 = (lane >> 4) * 4;
    #pragma unroll
    for (int n = 0; n < 4; ++n) {
        const int col = bcol + wc * 64 + n * 16 + fr;
        #pragma unroll
        for (int m = 0; m < 4; ++m) {
            const int row = brow + wr * 64 + m * 16 + r0;
            #pragma unroll
            for (int j = 0; j < 4; ++j)
                op[(size_t)(row + j) * 1024 + col] = 0.125f * acc[m][n][j];
        }
    }
}

extern "C" void kernel_launch(void* const* d_in, const int* in_sizes, int n_in,
                              void* d_out, int out_size, void* d_ws, size_t ws_size,
                              hipStream_t stream) {
    const float* rna  = (const float*)d_in[0];  // [8,1024,1280]
    const float* prot = (const float*)d_in[1];  // [8,1024,1344]
    const float* Wq   = (const float*)d_in[2];  // [512,1280]
    const float* bq   = (const float*)d_in[3];  // [512]
    const float* Wk   = (const float*)d_in[4];  // [512,1344]
    const float* bk   = (const float*)d_in[5];  // [512]
    const float* rb   = (const float*)d_in[6];  // [512] (flat idx == channel)

    __bf16* qws = (__bf16*)d_ws;                     // [8192,512] bf16 = 8 MB
    __bf16* kws = qws + (size_t)8192 * 512;          // [8192,512] bf16 = 8 MB
    __bf16* wqb = kws + (size_t)8192 * 512;          // [512,1280] bf16 (swizzled)
    __bf16* wkb = wqb + (size_t)512 * 1280;          // [512,1344] bf16 (swizzled)

    // chunks = 512*(160+168) = 167936 = 656 * 256
    wcvt<<<dim3(656), dim3(256), 0, stream>>>(Wq, Wk, wqb, wkb);
    proj_all<<<dim3(256), dim3(256), 0, stream>>>(rna, prot, wqb, wkb, bq, bk, rb, qws, kws);
    attn_kernel<<<dim3(8, 8, 8), dim3(256), 0, stream>>>(qws, kws, (float*)d_out);
}